// Round 4
// baseline (2421.614 us; speedup 1.0000x reference)
//
#include <hip/hip_runtime.h>

#define N_NODES 32768
#define DEG 16
#define IN_F 128
#define HIDF 256
#define N_GRAPHS 256
#define NPG 128
#define OUT_F 16

typedef unsigned short u16;
typedef unsigned int u32;
typedef __bf16 bf16x8 __attribute__((ext_vector_type(8)));
typedef float f32x4 __attribute__((ext_vector_type(4)));

__device__ __forceinline__ u16 f2bf(float f) {
  union { float f; unsigned u; } v; v.f = f;
  return (u16)((v.u + 0x7FFFu + ((v.u >> 16) & 1u)) >> 16);
}
__device__ __forceinline__ float bf2f(u16 b) {
  union { unsigned u; float f; } v; v.u = ((unsigned)b) << 16;
  return v.f;
}
__device__ __forceinline__ float sigm(float x) { return 1.0f / (1.0f + __expf(-x)); }
__device__ __forceinline__ float tanhfast(float x) {
  float e = __expf(2.0f * x);
  return (e - 1.0f) / (e + 1.0f);
}

// ---- prep kernels -------------------------------------------------------

__global__ void k_prep_x(const float* __restrict__ x, u16* __restrict__ out, int n4) {
  int i = blockIdx.x * blockDim.x + threadIdx.x;
  if (i < n4) {
    float4 v = ((const float4*)x)[i];
    ushort4 o;
    o.x = f2bf(v.x); o.y = f2bf(v.y); o.z = f2bf(v.z); o.w = f2bf(v.w);
    ((ushort4*)out)[i] = o;
  }
}

// Permuted LSTM weight layout:
//   np = w*(F/2) + l16*(F/32) + pass*(F/64) + ntp
// gate map: pass0 {gp0:i(0), gp1:g(2)}, pass1 {gp0:f(1), gp1:o(3)};
// within-gate feature = w*(F/8) + l16*FT + ft.   (FT=F/128)
__global__ void k_prep_perm(const float* __restrict__ Wi, const float* __restrict__ Wh,
                            const float* __restrict__ bi, const float* __restrict__ bh,
                            u16* __restrict__ Bxw, u16* __restrict__ Bhh,
                            float* __restrict__ biasw, int F) {
  int FT = F >> 7;
  int W2 = F >> 1, L2v = F >> 5, P2 = F >> 6;
  int total = 4 * F * F;
  for (int idx = blockIdx.x * blockDim.x + threadIdx.x; idx < total;
       idx += gridDim.x * blockDim.x) {
    int np = idx / F;
    int k = idx % F;
    int w = np / W2;      int rem = np % W2;
    int l16 = rem / L2v;  int r2 = rem % L2v;
    int pass = r2 / P2;   int ntp = r2 % P2;
    int gp = ntp / FT;    int ft = ntp % FT;
    int gate = (pass == 0) ? (gp == 0 ? 0 : 2) : (gp == 0 ? 1 : 3);
    int orig = gate * F + w * (F >> 3) + l16 * FT + ft;
    Bxw[idx] = f2bf(Wi[orig * F + k]);
    Bhh[idx] = f2bf(Wh[orig * F + k]);
    if (k == 0) biasw[np] = bi[orig] + bh[orig];
  }
}

__global__ void k_prep_cast(const float* __restrict__ Ws, const float* __restrict__ Wn,
                            u16* __restrict__ Bs, u16* __restrict__ Bn, int n) {
  int i = blockIdx.x * blockDim.x + threadIdx.x;
  if (i < n) { Bs[i] = f2bf(Ws[i]); Bn[i] = f2bf(Wn[i]); }
}

// ---- dense GEMM: C[M][NC] = bf16(A[M][K] @ B[NC][K]^T + bias) ------------
template <int K, int NC>
__launch_bounds__(256, 4)
__global__ void k_gemm(const u16* __restrict__ A, const u16* __restrict__ B,
                       const float* __restrict__ bias, u16* __restrict__ C) {
  constexpr int ROWB = 2 * K;
  __shared__ u16 lds[64 * K];
  char* ldsb = (char*)lds;
  const int tid = threadIdx.x;
  const int w = tid >> 6;
  const int lane = tid & 63;
  const int l16 = lane & 15, lq = lane >> 4;
  const int row0 = blockIdx.x * 64;
  const int col0 = blockIdx.y * 128;

  constexpr int CH = K / 8;
  constexpr int RPI = 256 / CH;
#pragma unroll
  for (int it = 0; it < 64 / RPI; ++it) {
    int r = tid / CH + it * RPI;
    int ch = tid % CH;
    bf16x8 v = *(const bf16x8*)(A + (size_t)(row0 + r) * K + ch * 8);
    int bo = r * ROWB + ((ch * 16) ^ ((r & 7) << 4));
    *(bf16x8*)(ldsb + bo) = v;
  }
  __syncthreads();

  f32x4 acc[4][2];
#pragma unroll
  for (int mt = 0; mt < 4; ++mt)
#pragma unroll
    for (int nt = 0; nt < 2; ++nt)
#pragma unroll
      for (int j = 0; j < 4; ++j) acc[mt][nt][j] = 0.f;

  for (int ks = 0; ks < K / 32; ++ks) {
    bf16x8 a[4];
#pragma unroll
    for (int mt = 0; mt < 4; ++mt) {
      int r = mt * 16 + l16;
      int bo = r * ROWB + (((ks * 32 + lq * 8) * 2) ^ ((r & 7) << 4));
      a[mt] = *(const bf16x8*)(ldsb + bo);
    }
#pragma unroll
    for (int nt = 0; nt < 2; ++nt) {
      int coln = col0 + w * 32 + nt * 16 + l16;
      bf16x8 b = *(const bf16x8*)(B + (size_t)coln * K + ks * 32 + lq * 8);
#pragma unroll
      for (int mt = 0; mt < 4; ++mt)
        acc[mt][nt] = __builtin_amdgcn_mfma_f32_16x16x32_bf16(a[mt], b, acc[mt][nt], 0, 0, 0);
    }
  }
#pragma unroll
  for (int mt = 0; mt < 4; ++mt)
#pragma unroll
    for (int nt = 0; nt < 2; ++nt) {
      int coln = col0 + w * 32 + nt * 16 + l16;
      float bb = bias[coln];
#pragma unroll
      for (int j = 0; j < 4; ++j) {
        int r = row0 + mt * 16 + lq * 4 + j;
        C[(size_t)r * NC + coln] = f2bf(acc[mt][nt][j] + bb);
      }
    }
}

// ---- recurrent LSTM aggregation + combine --------------------------------
// 8 waves x 32 nodes. KEY CHANGE vs prior rounds: no precomputed XW gather.
// Gather the neighbor's RAW feature row x[nbr] (F elems, 4x fewer bytes than
// the 4F XW row) into a double-buffered LDS xbuf, and fold x@Bxw into the
// MFMA chain: gates = [x_nbr, h] @ [Bxw; Bh]^T + bias(reg init).
// Gather: issue global loads at step start (8 transient VGPRs), ds_write
// after the MFMA chain -> HBM/L3 latency hides under compute; the per-step
// gather set is the F-wide feature array (16MB) which stays L3-resident.
// One barrier per step. t=0 skips the h-part (h==0).
template <int F>
__launch_bounds__(512, 4)
__global__ void k_recur(const u16* __restrict__ X,    // [N][F] node features (bf16)
                        const u16* __restrict__ XS,   // [N][HIDF] self-part + b
                        const int* __restrict__ nbr,  // [N][DEG]
                        const u16* __restrict__ Bxw,  // [4F][F] permuted rows
                        const u16* __restrict__ Bh,   // [4F][F] permuted rows
                        const float* __restrict__ bw, // [4F] permuted bias
                        const u16* __restrict__ Bn,   // [HIDF][F]
                        u16* __restrict__ out) {      // [N][HIDF]
  constexpr int FT = F / 128;
  constexpr int NTP = F / 64;   // per-pass ntp count
  constexpr int KS = F / 32;
  constexpr int ROWB = 2 * F;

  __shared__ __align__(16) u16 hbuf[2][32 * F];
  __shared__ __align__(16) u16 xbuf[2][32 * F];
  __shared__ __align__(16) int snbrT[DEG * 32];

  const int tid = threadIdx.x;
  const int w = tid >> 6;
  const int lane = tid & 63;
  const int l16 = lane & 15, lq = lane >> 4;
  const int node_base = blockIdx.x * 32;

  // gather geometry: 512 threads stage 32 rows x ROWB bytes
  const int grow = tid >> 4;              // 0..31 local node
  const int gcol = (tid & 15) * 16;       // byte offset, 16 lanes cover 256B
  const int gbo0 = grow * ROWB + (gcol ^ ((grow & 7) << 4));
  const int gbo1 = grow * ROWB + ((256 + gcol) ^ ((grow & 7) << 4));  // F==256

  // stage transposed neighbor table: snbrT[t][node]
  for (int i = tid; i < 32 * DEG; i += 512) {
    int r = i / DEG, t = i % DEG;
    snbrT[t * 32 + r] = nbr[(node_base + r) * DEG + t];
  }

  float c[2][FT][4];
#pragma unroll
  for (int mt = 0; mt < 2; ++mt)
#pragma unroll
    for (int ft = 0; ft < FT; ++ft)
#pragma unroll
      for (int j = 0; j < 4; ++j) c[mt][ft][j] = 0.f;

  __syncthreads();

  const int xwoff = w * (F / 2) + l16 * (F / 32);
  const u16* bxb = Bxw + (size_t)xwoff * F + lq * 8;
  const u16* bhb = Bh + (size_t)xwoff * F + lq * 8;

  float bwreg[2][NTP];
#pragma unroll
  for (int p = 0; p < 2; ++p)
#pragma unroll
    for (int n = 0; n < NTP; ++n) bwreg[p][n] = bw[xwoff + p * NTP + n];

  // prologue: stage x_nbr for t=0 into xbuf[0]
  {
    int nb0 = snbrT[grow];
    const char* src = (const char*)(X + (size_t)nb0 * F);
    bf16x8 g0 = *(const bf16x8*)(src + gcol);
    *(bf16x8*)((char*)xbuf[0] + gbo0) = g0;
    if constexpr (F == 256) {
      bf16x8 g1 = *(const bf16x8*)(src + 256 + gcol);
      *(bf16x8*)((char*)xbuf[0] + gbo1) = g1;
    }
  }
  __syncthreads();

#pragma unroll 1
  for (int t = 0; t < DEG; ++t) {
    const char* hrd = (const char*)hbuf[t & 1];
    const char* xrd = (const char*)xbuf[t & 1];
    char* hwr = (char*)hbuf[(t & 1) ^ 1];
    char* xwr = (char*)xbuf[(t & 1) ^ 1];

    // issue next-step x gather NOW; ds_write only after the MFMA chain
    bf16x8 g0, g1;
    const bool pf = (t + 1 < DEG);
    if (pf) {
      int nb2 = snbrT[(t + 1) * 32 + grow];
      const char* src = (const char*)(X + (size_t)nb2 * F);
      g0 = *(const bf16x8*)(src + gcol);
      if constexpr (F == 256) g1 = *(const bf16x8*)(src + 256 + gcol);
    }

    float ig[2][FT][4];
#pragma unroll
    for (int pass = 0; pass < 2; ++pass) {
      f32x4 acc[2][NTP];
#pragma unroll
      for (int mt = 0; mt < 2; ++mt)
#pragma unroll
        for (int ntp = 0; ntp < NTP; ++ntp)
#pragma unroll
          for (int j = 0; j < 4; ++j) acc[mt][ntp][j] = bwreg[pass][ntp];

      // x-part: gates += x_nbr @ Bxw^T
#pragma unroll 2
      for (int ks = 0; ks < KS; ++ks) {
        bf16x8 a[2];
#pragma unroll
        for (int mt = 0; mt < 2; ++mt) {
          int r = mt * 16 + l16;
          int bo = r * ROWB + (((ks * 32 + lq * 8) * 2) ^ ((r & 7) << 4));
          a[mt] = *(const bf16x8*)(xrd + bo);
        }
#pragma unroll
        for (int ntp = 0; ntp < NTP; ++ntp) {
          bf16x8 b = *(const bf16x8*)(bxb + (size_t)(pass * NTP + ntp) * F + ks * 32);
          acc[0][ntp] = __builtin_amdgcn_mfma_f32_16x16x32_bf16(a[0], b, acc[0][ntp], 0, 0, 0);
          acc[1][ntp] = __builtin_amdgcn_mfma_f32_16x16x32_bf16(a[1], b, acc[1][ntp], 0, 0, 0);
        }
      }
      // h-part: gates += h @ Bh^T   (h==0 at t=0)
      if (t > 0) {
#pragma unroll 2
        for (int ks = 0; ks < KS; ++ks) {
          bf16x8 a[2];
#pragma unroll
          for (int mt = 0; mt < 2; ++mt) {
            int r = mt * 16 + l16;
            int bo = r * ROWB + (((ks * 32 + lq * 8) * 2) ^ ((r & 7) << 4));
            a[mt] = *(const bf16x8*)(hrd + bo);
          }
#pragma unroll
          for (int ntp = 0; ntp < NTP; ++ntp) {
            bf16x8 b = *(const bf16x8*)(bhb + (size_t)(pass * NTP + ntp) * F + ks * 32);
            acc[0][ntp] = __builtin_amdgcn_mfma_f32_16x16x32_bf16(a[0], b, acc[0][ntp], 0, 0, 0);
            acc[1][ntp] = __builtin_amdgcn_mfma_f32_16x16x32_bf16(a[1], b, acc[1][ntp], 0, 0, 0);
          }
        }
      }

      if (pass == 0) {
        // gates i (ntp=ft) and g (ntp=FT+ft)
#pragma unroll
        for (int mt = 0; mt < 2; ++mt)
#pragma unroll
          for (int ft = 0; ft < FT; ++ft)
#pragma unroll
            for (int j = 0; j < 4; ++j)
              ig[mt][ft][j] = sigm(acc[mt][ft][j]) * tanhfast(acc[mt][FT + ft][j]);
      } else {
        // gates f (ntp=ft) and o (ntp=FT+ft)
#pragma unroll
        for (int mt = 0; mt < 2; ++mt)
#pragma unroll
          for (int j = 0; j < 4; ++j) {
            int m = mt * 16 + lq * 4 + j;
            if constexpr (FT == 1) {
              float cn = sigm(acc[mt][0][j]) * c[mt][0][j] + ig[mt][0][j];
              c[mt][0][j] = cn;
              float hn = sigm(acc[mt][1][j]) * tanhfast(cn);
              int fe = w * (F / 8) + l16;
              int bo = m * ROWB + ((fe * 2) ^ ((m & 7) << 4));
              *(u16*)(hwr + bo) = f2bf(hn);
            } else {
              float cn0 = sigm(acc[mt][0][j]) * c[mt][0][j] + ig[mt][0][j];
              float cn1 = sigm(acc[mt][1][j]) * c[mt][1][j] + ig[mt][1][j];
              c[mt][0][j] = cn0;
              c[mt][1][j] = cn1;
              float hn0 = sigm(acc[mt][FT][j]) * tanhfast(cn0);
              float hn1 = sigm(acc[mt][FT + 1][j]) * tanhfast(cn1);
              int fe = w * (F / 8) + l16 * 2;
              int bo = m * ROWB + ((fe * 2) ^ ((m & 7) << 4));
              *(u32*)(hwr + bo) = (u32)f2bf(hn0) | ((u32)f2bf(hn1) << 16);
            }
          }
      }
    }

    // land the prefetched x rows into the other xbuf
    if (pf) {
      *(bf16x8*)(xwr + gbo0) = g0;
      if constexpr (F == 256) *(bf16x8*)(xwr + gbo1) = g1;
    }
    __syncthreads();
  }

  // combine: out = relu(XS[node] + h16 @ Bn^T)   (DEG even -> h16 in hbuf[0])
  const char* hrd = (const char*)hbuf[0];
  f32x4 acc2[2][2];
#pragma unroll
  for (int mt = 0; mt < 2; ++mt)
#pragma unroll
    for (int nt = 0; nt < 2; ++nt) {
      int coln = w * 32 + nt * 16 + l16;
      u16 xsu[4];
#pragma unroll
      for (int j = 0; j < 4; ++j)
        xsu[j] = XS[(size_t)(node_base + mt * 16 + lq * 4 + j) * HIDF + coln];
#pragma unroll
      for (int j = 0; j < 4; ++j) acc2[mt][nt][j] = bf2f(xsu[j]);
    }

#pragma unroll 2
  for (int ks = 0; ks < KS; ++ks) {
    bf16x8 a[2];
#pragma unroll
    for (int mt = 0; mt < 2; ++mt) {
      int r = mt * 16 + l16;
      int bo = r * ROWB + (((ks * 32 + lq * 8) * 2) ^ ((r & 7) << 4));
      a[mt] = *(const bf16x8*)(hrd + bo);
    }
#pragma unroll
    for (int nt = 0; nt < 2; ++nt) {
      int coln = w * 32 + nt * 16 + l16;
      bf16x8 b = *(const bf16x8*)(Bn + (size_t)coln * F + ks * 32 + lq * 8);
      acc2[0][nt] = __builtin_amdgcn_mfma_f32_16x16x32_bf16(a[0], b, acc2[0][nt], 0, 0, 0);
      acc2[1][nt] = __builtin_amdgcn_mfma_f32_16x16x32_bf16(a[1], b, acc2[1][nt], 0, 0, 0);
    }
  }
#pragma unroll
  for (int mt = 0; mt < 2; ++mt)
#pragma unroll
    for (int nt = 0; nt < 2; ++nt) {
      int coln = w * 32 + nt * 16 + l16;
#pragma unroll
      for (int j = 0; j < 4; ++j) {
        int m = node_base + mt * 16 + lq * 4 + j;
        out[(size_t)m * HIDF + coln] = f2bf(fmaxf(acc2[mt][nt][j], 0.f));
      }
    }
}

// ---- mean-pool per graph + classifier -----------------------------------
__global__ void k_pool(const u16* __restrict__ h2, const float* __restrict__ Wc,
                       const float* __restrict__ bc, float* __restrict__ out) {
  __shared__ float hg[HIDF];
  int g = blockIdx.x;
  int tid = threadIdx.x;
  float s = 0.0f;
  for (int i = 0; i < NPG; ++i) s += bf2f(h2[(size_t)(g * NPG + i) * HIDF + tid]);
  hg[tid] = s * (1.0f / NPG);
  __syncthreads();
  if (tid < OUT_F) {
    float o = bc[tid];
    for (int fe = 0; fe < HIDF; ++fe) o += hg[fe] * Wc[tid * HIDF + fe];
    out[g * OUT_F + tid] = o;
  }
}

// ---- launch -------------------------------------------------------------
extern "C" void kernel_launch(void* const* d_in, const int* in_sizes, int n_in,
                              void* d_out, int out_size, void* d_ws, size_t ws_size,
                              hipStream_t stream) {
  const float* x   = (const float*)d_in[0];
  const int*   nbr = (const int*)d_in[1];
  const float* Wi1 = (const float*)d_in[2];
  const float* Wh1 = (const float*)d_in[3];
  const float* bi1 = (const float*)d_in[4];
  const float* bh1 = (const float*)d_in[5];
  const float* Ws1 = (const float*)d_in[6];
  const float* Wn1 = (const float*)d_in[7];
  const float* b1  = (const float*)d_in[8];
  const float* Wi2 = (const float*)d_in[9];
  const float* Wh2 = (const float*)d_in[10];
  const float* bi2 = (const float*)d_in[11];
  const float* bh2 = (const float*)d_in[12];
  const float* Ws2 = (const float*)d_in[13];
  const float* Wn2 = (const float*)d_in[14];
  const float* b2  = (const float*)d_in[15];
  const float* Wc  = (const float*)d_in[16];
  const float* bc  = (const float*)d_in[17];
  float* out = (float*)d_out;

  char* ws = (char*)d_ws;
  const size_t MB = 1u << 20;
  u16* x16 = (u16*)(ws + 0);          //  8 MB
  u16* XS1 = (u16*)(ws + 8 * MB);     // 16 MB
  u16* h1  = (u16*)(ws + 24 * MB);    // 16 MB
  u16* XS2 = (u16*)(ws + 40 * MB);    // 16 MB
  u16* h2  = (u16*)(ws + 56 * MB);    // 16 MB
  char* wr = ws + 72 * MB;
  size_t off = 0;
  auto alloc = [&](size_t bytes) { void* p = wr + off; off += (bytes + 255) & ~(size_t)255; return p; };
  u16*   Bxw1 = (u16*)alloc(512 * 128 * 2);
  u16*   Bh1  = (u16*)alloc(512 * 128 * 2);
  float* bw1  = (float*)alloc(512 * 4);
  u16*   Bs1  = (u16*)alloc(256 * 128 * 2);
  u16*   Bn1  = (u16*)alloc(256 * 128 * 2);
  u16*   Bxw2 = (u16*)alloc(1024 * 256 * 2);
  u16*   Bh2  = (u16*)alloc(1024 * 256 * 2);
  float* bw2  = (float*)alloc(1024 * 4);
  u16*   Bs2  = (u16*)alloc(256 * 256 * 2);
  u16*   Bn2  = (u16*)alloc(256 * 256 * 2);

  k_prep_x<<<dim3(N_NODES * IN_F / 4 / 256), dim3(256), 0, stream>>>(x, x16, N_NODES * IN_F / 4);
  k_prep_perm<<<dim3(256), dim3(256), 0, stream>>>(Wi1, Wh1, bi1, bh1, Bxw1, Bh1, bw1, IN_F);
  k_prep_perm<<<dim3(1024), dim3(256), 0, stream>>>(Wi2, Wh2, bi2, bh2, Bxw2, Bh2, bw2, HIDF);
  k_prep_cast<<<dim3(128), dim3(256), 0, stream>>>(Ws1, Wn1, Bs1, Bn1, 256 * 128);
  k_prep_cast<<<dim3(256), dim3(256), 0, stream>>>(Ws2, Wn2, Bs2, Bn2, 256 * 256);

  k_gemm<128, 256><<<dim3(N_NODES / 64, 2), dim3(256), 0, stream>>>(x16, Bs1, b1, XS1);
  k_recur<IN_F><<<dim3(N_NODES / 32), dim3(512), 0, stream>>>(x16, XS1, nbr, Bxw1, Bh1, bw1, Bn1, h1);
  k_gemm<256, 256><<<dim3(N_NODES / 64, 2), dim3(256), 0, stream>>>(h1, Bs2, b2, XS2);
  k_recur<HIDF><<<dim3(N_NODES / 32), dim3(512), 0, stream>>>(h1, XS2, nbr, Bxw2, Bh2, bw2, Bn2, h2);

  k_pool<<<dim3(N_GRAPHS), dim3(256), 0, stream>>>(h2, Wc, bc, out);
}

// Round 5
// 1464.746 us; speedup vs baseline: 1.6533x; 1.6533x over previous
//
#include <hip/hip_runtime.h>

#define N_NODES 32768
#define DEG 16
#define IN_F 128
#define HIDF 256
#define N_GRAPHS 256
#define NPG 128
#define OUT_F 16

typedef unsigned short u16;
typedef unsigned int u32;
typedef __bf16 bf16x8 __attribute__((ext_vector_type(8)));
typedef float f32x4 __attribute__((ext_vector_type(4)));
typedef u16 u16x4 __attribute__((ext_vector_type(4)));
typedef u16 u16x8 __attribute__((ext_vector_type(8)));

__device__ __forceinline__ u16 f2bf(float f) {
  union { float f; unsigned u; } v; v.f = f;
  return (u16)((v.u + 0x7FFFu + ((v.u >> 16) & 1u)) >> 16);
}
__device__ __forceinline__ float bf2f(u16 b) {
  union { unsigned u; float f; } v; v.u = ((unsigned)b) << 16;
  return v.f;
}
__device__ __forceinline__ float sigm(float x) { return 1.0f / (1.0f + __expf(-x)); }
__device__ __forceinline__ float tanhfast(float x) {
  float e = __expf(2.0f * x);
  return (e - 1.0f) / (e + 1.0f);
}

// ---- prep kernels -------------------------------------------------------

__global__ void k_prep_x(const float* __restrict__ x, u16* __restrict__ out, int n4) {
  int i = blockIdx.x * blockDim.x + threadIdx.x;
  if (i < n4) {
    float4 v = ((const float4*)x)[i];
    ushort4 o;
    o.x = f2bf(v.x); o.y = f2bf(v.y); o.z = f2bf(v.z); o.w = f2bf(v.w);
    ((ushort4*)out)[i] = o;
  }
}

// Gate-interleaved weight rows: p = fe*4 + gate (gate order i,f,g,o).
// So a 16x16 MFMA C-fragment's j index (rows lq*4+j) IS the gate index.
__global__ void k_prep_wg(const float* __restrict__ Wi, const float* __restrict__ Wh,
                          const float* __restrict__ bi, const float* __restrict__ bh,
                          u16* __restrict__ Wip, u16* __restrict__ Whp,
                          float* __restrict__ bwp, int F) {
  int total = 4 * F * F;
  for (int idx = blockIdx.x * blockDim.x + threadIdx.x; idx < total;
       idx += gridDim.x * blockDim.x) {
    int p = idx / F, k = idx % F;
    int fe = p >> 2, g = p & 3;
    int orig = g * F + fe;
    Wip[idx] = f2bf(Wi[orig * F + k]);
    Whp[idx] = f2bf(Wh[orig * F + k]);
    if (k == 0) bwp[p] = bi[orig] + bh[orig];
  }
}

__global__ void k_prep_cast(const float* __restrict__ Ws, const float* __restrict__ Wn,
                            u16* __restrict__ Bs, u16* __restrict__ Bn, int n) {
  int i = blockIdx.x * blockDim.x + threadIdx.x;
  if (i < n) { Bs[i] = f2bf(Ws[i]); Bn[i] = f2bf(Wn[i]); }
}

// ---- dense GEMM: C[M][NC] = bf16(A[M][K] @ B[NC][K]^T + bias) ------------
template <int K, int NC>
__launch_bounds__(256, 4)
__global__ void k_gemm(const u16* __restrict__ A, const u16* __restrict__ B,
                       const float* __restrict__ bias, u16* __restrict__ C) {
  constexpr int ROWB = 2 * K;
  __shared__ u16 lds[64 * K];
  char* ldsb = (char*)lds;
  const int tid = threadIdx.x;
  const int w = tid >> 6;
  const int lane = tid & 63;
  const int l16 = lane & 15, lq = lane >> 4;
  const int row0 = blockIdx.x * 64;
  const int col0 = blockIdx.y * 128;

  constexpr int CH = K / 8;
  constexpr int RPI = 256 / CH;
#pragma unroll
  for (int it = 0; it < 64 / RPI; ++it) {
    int r = tid / CH + it * RPI;
    int ch = tid % CH;
    bf16x8 v = *(const bf16x8*)(A + (size_t)(row0 + r) * K + ch * 8);
    int bo = r * ROWB + ((ch * 16) ^ ((r & 7) << 4));
    *(bf16x8*)(ldsb + bo) = v;
  }
  __syncthreads();

  f32x4 acc[4][2];
#pragma unroll
  for (int mt = 0; mt < 4; ++mt)
#pragma unroll
    for (int nt = 0; nt < 2; ++nt)
#pragma unroll
      for (int j = 0; j < 4; ++j) acc[mt][nt][j] = 0.f;

  for (int ks = 0; ks < K / 32; ++ks) {
    bf16x8 a[4];
#pragma unroll
    for (int mt = 0; mt < 4; ++mt) {
      int r = mt * 16 + l16;
      int bo = r * ROWB + (((ks * 32 + lq * 8) * 2) ^ ((r & 7) << 4));
      a[mt] = *(const bf16x8*)(ldsb + bo);
    }
#pragma unroll
    for (int nt = 0; nt < 2; ++nt) {
      int coln = col0 + w * 32 + nt * 16 + l16;
      bf16x8 b = *(const bf16x8*)(B + (size_t)coln * K + ks * 32 + lq * 8);
#pragma unroll
      for (int mt = 0; mt < 4; ++mt)
        acc[mt][nt] = __builtin_amdgcn_mfma_f32_16x16x32_bf16(a[mt], b, acc[mt][nt], 0, 0, 0);
    }
  }
#pragma unroll
  for (int mt = 0; mt < 4; ++mt)
#pragma unroll
    for (int nt = 0; nt < 2; ++nt) {
      int coln = col0 + w * 32 + nt * 16 + l16;
      float bb = bias[coln];
#pragma unroll
      for (int j = 0; j < 4; ++j) {
        int r = row0 + mt * 16 + lq * 4 + j;
        C[(size_t)r * NC + coln] = f2bf(acc[mt][nt][j] + bb);
      }
    }
}

// ---- combine GEMM: C[r][coln] = relu_bf16(XS[r][coln] + A[r]@B[coln]) ----
template <int K>
__launch_bounds__(256, 4)
__global__ void k_comb(const u16* __restrict__ A, const u16* __restrict__ B,
                       const u16* __restrict__ XS, u16* __restrict__ C) {
  constexpr int ROWB = 2 * K;
  __shared__ u16 lds[64 * K];
  char* ldsb = (char*)lds;
  const int tid = threadIdx.x;
  const int w = tid >> 6;
  const int lane = tid & 63;
  const int l16 = lane & 15, lq = lane >> 4;
  const int row0 = blockIdx.x * 64;
  const int col0 = blockIdx.y * 128;

  constexpr int CH = K / 8;
  constexpr int RPI = 256 / CH;
#pragma unroll
  for (int it = 0; it < 64 / RPI; ++it) {
    int r = tid / CH + it * RPI;
    int ch = tid % CH;
    bf16x8 v = *(const bf16x8*)(A + (size_t)(row0 + r) * K + ch * 8);
    int bo = r * ROWB + ((ch * 16) ^ ((r & 7) << 4));
    *(bf16x8*)(ldsb + bo) = v;
  }
  __syncthreads();

  f32x4 acc[4][2];
#pragma unroll
  for (int mt = 0; mt < 4; ++mt)
#pragma unroll
    for (int nt = 0; nt < 2; ++nt)
#pragma unroll
      for (int j = 0; j < 4; ++j) acc[mt][nt][j] = 0.f;

  for (int ks = 0; ks < K / 32; ++ks) {
    bf16x8 a[4];
#pragma unroll
    for (int mt = 0; mt < 4; ++mt) {
      int r = mt * 16 + l16;
      int bo = r * ROWB + (((ks * 32 + lq * 8) * 2) ^ ((r & 7) << 4));
      a[mt] = *(const bf16x8*)(ldsb + bo);
    }
#pragma unroll
    for (int nt = 0; nt < 2; ++nt) {
      int coln = col0 + w * 32 + nt * 16 + l16;
      bf16x8 b = *(const bf16x8*)(B + (size_t)coln * K + ks * 32 + lq * 8);
#pragma unroll
      for (int mt = 0; mt < 4; ++mt)
        acc[mt][nt] = __builtin_amdgcn_mfma_f32_16x16x32_bf16(a[mt], b, acc[mt][nt], 0, 0, 0);
    }
  }
#pragma unroll
  for (int mt = 0; mt < 4; ++mt)
#pragma unroll
    for (int nt = 0; nt < 2; ++nt) {
      int coln = col0 + w * 32 + nt * 16 + l16;
#pragma unroll
      for (int j = 0; j < 4; ++j) {
        int r = row0 + mt * 16 + lq * 4 + j;
        float v = acc[mt][nt][j] + bf2f(XS[(size_t)r * HIDF + coln]);
        C[(size_t)r * HIDF + coln] = f2bf(fmaxf(v, 0.f));
      }
    }
}

// ---- one LSTM step as a dense GEMM + fused cell update -------------------
// gates^T[4F][N] = Whp @ h_t rows;  tile BM=128 gate-rows x BN=128 nodes,
// 512 thr / 8 waves (wr=w>>2 owns 64 rows, wc=w&3 owns 32 cols).
// Gate-interleaved rows (p=fe*4+g) make the C-fragment's j index the gate
// index -> whole LSTM cell update is in-lane. XW (precomputed x@Wi+b, same
// layout) is one 8B gather per fragment, prefetched before the K-loop.
// c state is [F][N] f32 (in-lane coalesced); h' transposed back to
// node-major via a padded LDS tile. t=0 (T0): h==0 -> skip GEMM entirely.
template <int F, bool T0>
__launch_bounds__(512, 3)
__global__ void k_step(const u16* __restrict__ hprev, // [N][F] node-major
                       const u16* __restrict__ XW,    // [N][4F] gate-interleaved
                       const u16* __restrict__ Whp,   // [4F][F]
                       const int* __restrict__ nbr,   // [N][DEG]
                       int t,
                       float* __restrict__ cT,        // [F][N] f32
                       u16* __restrict__ hnext) {     // [N][F] node-major
  constexpr int ROWB = 2 * F;
  constexpr int KS = F / 32;
  __shared__ __align__(16) u16 lds[128 * F];
  __shared__ __align__(16) u16 tl[128 * 40];   // [node 128][fe 32 + pad 8]
  char* ldsb = (char*)lds;
  const int tid = threadIdx.x;
  const int w = tid >> 6;
  const int wr = w >> 2, wc = w & 3;
  const int lane = tid & 63;
  const int l16 = lane & 15, lq = lane >> 4;
  const int row0 = blockIdx.x * 128;   // gate-row base
  const int col0 = blockIdx.y * 128;   // node base
  const int feb = row0 >> 2;

  if constexpr (!T0) {
    constexpr int CH = F / 8;
    constexpr int RPI = 512 / CH;
#pragma unroll
    for (int it = 0; it < 128 / RPI; ++it) {
      int r = tid / CH + it * RPI;
      int ch = tid % CH;
      bf16x8 v = *(const bf16x8*)(Whp + (size_t)(row0 + r) * F + ch * 8);
      int bo = r * ROWB + ((ch * 16) ^ ((r & 7) << 4));
      *(bf16x8*)(ldsb + bo) = v;
    }
    __syncthreads();
  }

  // prefetch: neighbor ids, XW fragments (8B each), c state
  int nb[2];
#pragma unroll
  for (int nt = 0; nt < 2; ++nt) {
    int n = col0 + wc * 32 + nt * 16 + l16;
    nb[nt] = nbr[(size_t)n * DEG + t];
  }
  u16x4 xw[4][2];
  float cold[4][2];
#pragma unroll
  for (int mt = 0; mt < 4; ++mt)
#pragma unroll
    for (int nt = 0; nt < 2; ++nt) {
      int fe = feb + wr * 16 + mt * 4 + lq;
      xw[mt][nt] = *(const u16x4*)(XW + (size_t)nb[nt] * (4 * F) + (size_t)fe * 4);
      if constexpr (!T0) {
        int n = col0 + wc * 32 + nt * 16 + l16;
        cold[mt][nt] = cT[(size_t)fe * N_NODES + n];
      }
    }

  f32x4 acc[4][2];
#pragma unroll
  for (int mt = 0; mt < 4; ++mt)
#pragma unroll
    for (int nt = 0; nt < 2; ++nt)
#pragma unroll
      for (int j = 0; j < 4; ++j) acc[mt][nt][j] = 0.f;

  if constexpr (!T0) {
    const u16* hb0 = hprev + (size_t)(col0 + wc * 32 + l16) * F + lq * 8;
    const u16* hb1 = hb0 + (size_t)16 * F;
#pragma unroll
    for (int ks = 0; ks < KS; ++ks) {
      bf16x8 a[4];
#pragma unroll
      for (int mt = 0; mt < 4; ++mt) {
        int r = wr * 64 + mt * 16 + l16;
        int bo = r * ROWB + (((ks * 32 + lq * 8) * 2) ^ ((r & 7) << 4));
        a[mt] = *(const bf16x8*)(ldsb + bo);
      }
      bf16x8 b0 = *(const bf16x8*)(hb0 + ks * 32);
      bf16x8 b1 = *(const bf16x8*)(hb1 + ks * 32);
#pragma unroll
      for (int mt = 0; mt < 4; ++mt) {
        acc[mt][0] = __builtin_amdgcn_mfma_f32_16x16x32_bf16(a[mt], b0, acc[mt][0], 0, 0, 0);
        acc[mt][1] = __builtin_amdgcn_mfma_f32_16x16x32_bf16(a[mt], b1, acc[mt][1], 0, 0, 0);
      }
    }
  }

  // fused LSTM cell update (all in-lane: j = gate index)
#pragma unroll
  for (int mt = 0; mt < 4; ++mt)
#pragma unroll
    for (int nt = 0; nt < 2; ++nt) {
      int fe = feb + wr * 16 + mt * 4 + lq;
      int n = col0 + wc * 32 + nt * 16 + l16;
      float pi = acc[mt][nt][0] + bf2f(xw[mt][nt][0]);
      float pf = acc[mt][nt][1] + bf2f(xw[mt][nt][1]);
      float pg = acc[mt][nt][2] + bf2f(xw[mt][nt][2]);
      float po = acc[mt][nt][3] + bf2f(xw[mt][nt][3]);
      float cn;
      if constexpr (T0) cn = sigm(pi) * tanhfast(pg);
      else              cn = sigm(pf) * cold[mt][nt] + sigm(pi) * tanhfast(pg);
      float hn = sigm(po) * tanhfast(cn);
      cT[(size_t)fe * N_NODES + n] = cn;
      tl[(n - col0) * 40 + (fe - feb)] = f2bf(hn);
    }
  __syncthreads();

  // transposed write back to node-major hnext (4 threads per node, 16B each)
  {
    int nloc = tid >> 2, q = tid & 3;
    u16x8 v = *(const u16x8*)&tl[nloc * 40 + q * 8];
    *(u16x8*)(hnext + (size_t)(col0 + nloc) * F + feb + q * 8) = v;
  }
}

// ---- mean-pool per graph + classifier -----------------------------------
__global__ void k_pool(const u16* __restrict__ h2, const float* __restrict__ Wc,
                       const float* __restrict__ bc, float* __restrict__ out) {
  __shared__ float hg[HIDF];
  int g = blockIdx.x;
  int tid = threadIdx.x;
  float s = 0.0f;
  for (int i = 0; i < NPG; ++i) s += bf2f(h2[(size_t)(g * NPG + i) * HIDF + tid]);
  hg[tid] = s * (1.0f / NPG);
  __syncthreads();
  if (tid < OUT_F) {
    float o = bc[tid];
    for (int fe = 0; fe < HIDF; ++fe) o += hg[fe] * Wc[tid * HIDF + fe];
    out[g * OUT_F + tid] = o;
  }
}

// ---- launch -------------------------------------------------------------
extern "C" void kernel_launch(void* const* d_in, const int* in_sizes, int n_in,
                              void* d_out, int out_size, void* d_ws, size_t ws_size,
                              hipStream_t stream) {
  const float* x   = (const float*)d_in[0];
  const int*   nbr = (const int*)d_in[1];
  const float* Wi1 = (const float*)d_in[2];
  const float* Wh1 = (const float*)d_in[3];
  const float* bi1 = (const float*)d_in[4];
  const float* bh1 = (const float*)d_in[5];
  const float* Ws1 = (const float*)d_in[6];
  const float* Wn1 = (const float*)d_in[7];
  const float* b1  = (const float*)d_in[8];
  const float* Wi2 = (const float*)d_in[9];
  const float* Wh2 = (const float*)d_in[10];
  const float* bi2 = (const float*)d_in[11];
  const float* bh2 = (const float*)d_in[12];
  const float* Ws2 = (const float*)d_in[13];
  const float* Wn2 = (const float*)d_in[14];
  const float* b2  = (const float*)d_in[15];
  const float* Wc  = (const float*)d_in[16];
  const float* bc  = (const float*)d_in[17];
  float* out = (float*)d_out;

  char* ws = (char*)d_ws;
  const size_t MB = 1u << 20;
  // liveness-packed layout (high-water ~154MB):
  u16*   x16 = (u16*)(ws + 0);          //  8 MB, dead after XW1/XS1
  u16*   XW1 = (u16*)(ws + 8 * MB);     // 32 MB, dead after layer-1 steps
  u16*   XS1 = (u16*)(ws + 40 * MB);    // 16 MB; X2 written in-place by comb1
  u16*   X2  = XS1;
  u16*   hA1 = (u16*)(ws + 56 * MB);    //  8 MB
  u16*   hB1 = (u16*)(ws + 64 * MB);    //  8 MB
  float* c1  = (float*)(ws + 72 * MB);  // 16 MB f32 [128][N]
  u16*   XW2 = (u16*)(ws + 88 * MB);    // 64 MB
  u16*   XS2 = (u16*)(ws + 64 * MB);    // 16 MB (over hB1+c1, dead after comb1)
  u16*   h2o = XS2;                     // comb2 in-place
  u16*   hA2 = (u16*)(ws + 0);          // 16 MB (over x16+XW1-start, dead)
  u16*   hB2 = (u16*)(ws + 16 * MB);    // 16 MB (over XW1, dead)
  float* c2  = (float*)(ws + 32 * MB);  // 32 MB (over XW1/X2/hA1, dead)
  char* wr = ws + 152 * MB;
  size_t off = 0;
  auto alloc = [&](size_t bytes) { void* p = wr + off; off += (bytes + 255) & ~(size_t)255; return p; };
  u16*   Wip1 = (u16*)alloc(512 * 128 * 2);
  u16*   Whp1 = (u16*)alloc(512 * 128 * 2);
  float* bwp1 = (float*)alloc(512 * 4);
  u16*   Bs1  = (u16*)alloc(256 * 128 * 2);
  u16*   Bn1  = (u16*)alloc(256 * 128 * 2);
  u16*   Wip2 = (u16*)alloc(1024 * 256 * 2);
  u16*   Whp2 = (u16*)alloc(1024 * 256 * 2);
  float* bwp2 = (float*)alloc(1024 * 4);
  u16*   Bs2  = (u16*)alloc(256 * 256 * 2);
  u16*   Bn2  = (u16*)alloc(256 * 256 * 2);

  k_prep_x<<<dim3(N_NODES * IN_F / 4 / 256), dim3(256), 0, stream>>>(x, x16, N_NODES * IN_F / 4);
  k_prep_wg<<<dim3(256), dim3(256), 0, stream>>>(Wi1, Wh1, bi1, bh1, Wip1, Whp1, bwp1, IN_F);
  k_prep_wg<<<dim3(1024), dim3(256), 0, stream>>>(Wi2, Wh2, bi2, bh2, Wip2, Whp2, bwp2, HIDF);
  k_prep_cast<<<dim3(128), dim3(256), 0, stream>>>(Ws1, Wn1, Bs1, Bn1, 256 * 128);
  k_prep_cast<<<dim3(256), dim3(256), 0, stream>>>(Ws2, Wn2, Bs2, Bn2, 256 * 256);

  // ---- layer 1 ----
  k_gemm<128, 512><<<dim3(N_NODES / 64, 4), dim3(256), 0, stream>>>(x16, Wip1, bwp1, XW1);
  k_gemm<128, 256><<<dim3(N_NODES / 64, 2), dim3(256), 0, stream>>>(x16, Bs1, b1, XS1);
  {
    k_step<IN_F, true><<<dim3(4, N_NODES / 128), dim3(512), 0, stream>>>(
        hA1, XW1, Whp1, nbr, 0, c1, hA1);
    u16* hc = hA1; u16* hn = hB1;
    for (int t = 1; t < DEG; ++t) {
      k_step<IN_F, false><<<dim3(4, N_NODES / 128), dim3(512), 0, stream>>>(
          hc, XW1, Whp1, nbr, t, c1, hn);
      u16* tmp = hc; hc = hn; hn = tmp;
    }
    // DEG=16 -> final h1 in hB1 (hc)
    k_comb<128><<<dim3(N_NODES / 64, 2), dim3(256), 0, stream>>>(hc, Bn1, XS1, X2);
  }

  // ---- layer 2 ----
  k_gemm<256, 1024><<<dim3(N_NODES / 64, 8), dim3(256), 0, stream>>>(X2, Wip2, bwp2, XW2);
  k_gemm<256, 256><<<dim3(N_NODES / 64, 2), dim3(256), 0, stream>>>(X2, Bs2, b2, XS2);
  {
    k_step<HIDF, true><<<dim3(8, N_NODES / 128), dim3(512), 0, stream>>>(
        hA2, XW2, Whp2, nbr, 0, c2, hA2);
    u16* hc = hA2; u16* hn = hB2;
    for (int t = 1; t < DEG; ++t) {
      k_step<HIDF, false><<<dim3(8, N_NODES / 128), dim3(512), 0, stream>>>(
          hc, XW2, Whp2, nbr, t, c2, hn);
      u16* tmp = hc; hc = hn; hn = tmp;
    }
    k_comb<256><<<dim3(N_NODES / 64, 2), dim3(256), 0, stream>>>(hc, Bn2, XS2, h2o);
  }

  k_pool<<<dim3(N_GRAPHS), dim3(256), 0, stream>>>(h2o, Wc, bc, out);
}

// Round 6
// 1461.226 us; speedup vs baseline: 1.6572x; 1.0024x over previous
//
#include <hip/hip_runtime.h>

#define N_NODES 32768
#define DEG 16
#define IN_F 128
#define HIDF 256
#define N_GRAPHS 256
#define NPG 128
#define OUT_F 16

typedef unsigned short u16;
typedef unsigned int u32;
typedef __bf16 bf16x8 __attribute__((ext_vector_type(8)));
typedef float f32x4 __attribute__((ext_vector_type(4)));
typedef u16 u16x4 __attribute__((ext_vector_type(4)));
typedef u16 u16x8 __attribute__((ext_vector_type(8)));

__device__ __forceinline__ u16 f2bf(float f) {
  union { float f; unsigned u; } v; v.f = f;
  return (u16)((v.u + 0x7FFFu + ((v.u >> 16) & 1u)) >> 16);
}
__device__ __forceinline__ float bf2f(u16 b) {
  union { unsigned u; float f; } v; v.u = ((unsigned)b) << 16;
  return v.f;
}
__device__ __forceinline__ float sigm(float x) { return 1.0f / (1.0f + __expf(-x)); }
__device__ __forceinline__ float tanhfast(float x) {
  float e = __expf(2.0f * x);
  return (e - 1.0f) / (e + 1.0f);
}

// ---- prep kernels -------------------------------------------------------

__global__ void k_prep_x(const float* __restrict__ x, u16* __restrict__ out, int n4) {
  int i = blockIdx.x * blockDim.x + threadIdx.x;
  if (i < n4) {
    float4 v = ((const float4*)x)[i];
    ushort4 o;
    o.x = f2bf(v.x); o.y = f2bf(v.y); o.z = f2bf(v.z); o.w = f2bf(v.w);
    ((ushort4*)out)[i] = o;
  }
}

// Gate-interleaved weight rows: p = fe*4 + gate (gate order i,f,g,o).
// So a 16x16 MFMA C-fragment's j index (rows lq*4+j) IS the gate index.
__global__ void k_prep_wg(const float* __restrict__ Wi, const float* __restrict__ Wh,
                          const float* __restrict__ bi, const float* __restrict__ bh,
                          u16* __restrict__ Wip, u16* __restrict__ Whp,
                          float* __restrict__ bwp, int F) {
  int total = 4 * F * F;
  for (int idx = blockIdx.x * blockDim.x + threadIdx.x; idx < total;
       idx += gridDim.x * blockDim.x) {
    int p = idx / F, k = idx % F;
    int fe = p >> 2, g = p & 3;
    int orig = g * F + fe;
    Wip[idx] = f2bf(Wi[orig * F + k]);
    Whp[idx] = f2bf(Wh[orig * F + k]);
    if (k == 0) bwp[p] = bi[orig] + bh[orig];
  }
}

__global__ void k_prep_cast(const float* __restrict__ Ws, const float* __restrict__ Wn,
                            u16* __restrict__ Bs, u16* __restrict__ Bn, int n) {
  int i = blockIdx.x * blockDim.x + threadIdx.x;
  if (i < n) { Bs[i] = f2bf(Ws[i]); Bn[i] = f2bf(Wn[i]); }
}

// ---- dense GEMM: C[M][NC] = bf16(A[M][K] @ B[NC][K]^T + bias) ------------
template <int K, int NC>
__launch_bounds__(256, 4)
__global__ void k_gemm(const u16* __restrict__ A, const u16* __restrict__ B,
                       const float* __restrict__ bias, u16* __restrict__ C) {
  constexpr int ROWB = 2 * K;
  __shared__ u16 lds[64 * K];
  char* ldsb = (char*)lds;
  const int tid = threadIdx.x;
  const int w = tid >> 6;
  const int lane = tid & 63;
  const int l16 = lane & 15, lq = lane >> 4;
  const int row0 = blockIdx.x * 64;
  const int col0 = blockIdx.y * 128;

  constexpr int CH = K / 8;
  constexpr int RPI = 256 / CH;
#pragma unroll
  for (int it = 0; it < 64 / RPI; ++it) {
    int r = tid / CH + it * RPI;
    int ch = tid % CH;
    bf16x8 v = *(const bf16x8*)(A + (size_t)(row0 + r) * K + ch * 8);
    int bo = r * ROWB + ((ch * 16) ^ ((r & 7) << 4));
    *(bf16x8*)(ldsb + bo) = v;
  }
  __syncthreads();

  f32x4 acc[4][2];
#pragma unroll
  for (int mt = 0; mt < 4; ++mt)
#pragma unroll
    for (int nt = 0; nt < 2; ++nt)
#pragma unroll
      for (int j = 0; j < 4; ++j) acc[mt][nt][j] = 0.f;

  for (int ks = 0; ks < K / 32; ++ks) {
    bf16x8 a[4];
#pragma unroll
    for (int mt = 0; mt < 4; ++mt) {
      int r = mt * 16 + l16;
      int bo = r * ROWB + (((ks * 32 + lq * 8) * 2) ^ ((r & 7) << 4));
      a[mt] = *(const bf16x8*)(ldsb + bo);
    }
#pragma unroll
    for (int nt = 0; nt < 2; ++nt) {
      int coln = col0 + w * 32 + nt * 16 + l16;
      bf16x8 b = *(const bf16x8*)(B + (size_t)coln * K + ks * 32 + lq * 8);
#pragma unroll
      for (int mt = 0; mt < 4; ++mt)
        acc[mt][nt] = __builtin_amdgcn_mfma_f32_16x16x32_bf16(a[mt], b, acc[mt][nt], 0, 0, 0);
    }
  }
#pragma unroll
  for (int mt = 0; mt < 4; ++mt)
#pragma unroll
    for (int nt = 0; nt < 2; ++nt) {
      int coln = col0 + w * 32 + nt * 16 + l16;
      float bb = bias[coln];
#pragma unroll
      for (int j = 0; j < 4; ++j) {
        int r = row0 + mt * 16 + lq * 4 + j;
        C[(size_t)r * NC + coln] = f2bf(acc[mt][nt][j] + bb);
      }
    }
}

// ---- combine GEMM: C[r][coln] = relu_bf16(XS[r][coln] + A[r]@B[coln]) ----
template <int K>
__launch_bounds__(256, 4)
__global__ void k_comb(const u16* __restrict__ A, const u16* __restrict__ B,
                       const u16* __restrict__ XS, u16* __restrict__ C) {
  constexpr int ROWB = 2 * K;
  __shared__ u16 lds[64 * K];
  char* ldsb = (char*)lds;
  const int tid = threadIdx.x;
  const int w = tid >> 6;
  const int lane = tid & 63;
  const int l16 = lane & 15, lq = lane >> 4;
  const int row0 = blockIdx.x * 64;
  const int col0 = blockIdx.y * 128;

  constexpr int CH = K / 8;
  constexpr int RPI = 256 / CH;
#pragma unroll
  for (int it = 0; it < 64 / RPI; ++it) {
    int r = tid / CH + it * RPI;
    int ch = tid % CH;
    bf16x8 v = *(const bf16x8*)(A + (size_t)(row0 + r) * K + ch * 8);
    int bo = r * ROWB + ((ch * 16) ^ ((r & 7) << 4));
    *(bf16x8*)(ldsb + bo) = v;
  }
  __syncthreads();

  f32x4 acc[4][2];
#pragma unroll
  for (int mt = 0; mt < 4; ++mt)
#pragma unroll
    for (int nt = 0; nt < 2; ++nt)
#pragma unroll
      for (int j = 0; j < 4; ++j) acc[mt][nt][j] = 0.f;

  for (int ks = 0; ks < K / 32; ++ks) {
    bf16x8 a[4];
#pragma unroll
    for (int mt = 0; mt < 4; ++mt) {
      int r = mt * 16 + l16;
      int bo = r * ROWB + (((ks * 32 + lq * 8) * 2) ^ ((r & 7) << 4));
      a[mt] = *(const bf16x8*)(ldsb + bo);
    }
#pragma unroll
    for (int nt = 0; nt < 2; ++nt) {
      int coln = col0 + w * 32 + nt * 16 + l16;
      bf16x8 b = *(const bf16x8*)(B + (size_t)coln * K + ks * 32 + lq * 8);
#pragma unroll
      for (int mt = 0; mt < 4; ++mt)
        acc[mt][nt] = __builtin_amdgcn_mfma_f32_16x16x32_bf16(a[mt], b, acc[mt][nt], 0, 0, 0);
    }
  }
#pragma unroll
  for (int mt = 0; mt < 4; ++mt)
#pragma unroll
    for (int nt = 0; nt < 2; ++nt) {
      int coln = col0 + w * 32 + nt * 16 + l16;
#pragma unroll
      for (int j = 0; j < 4; ++j) {
        int r = row0 + mt * 16 + lq * 4 + j;
        float v = acc[mt][nt][j] + bf2f(XS[(size_t)r * HIDF + coln]);
        C[(size_t)r * HIDF + coln] = f2bf(fmaxf(v, 0.f));
      }
    }
}

// ---- one LSTM step as a dense GEMM + fused cell update -------------------
// Occupancy-retiled: BM=64 gate-rows x BN=128 nodes, 512 thr / 8 waves,
// wave-tile 64 rows x 16 cols (wave w owns nodes col0+w*16..+16; dupB=1,
// h read once per block; A duplication absorbed by the LDS pipe).
// LDS = 32KB A-stage + 6KB transpose tile -> 4 blocks/CU; launch_bounds
// (512,8) forces VGPR<=64 for full 32-wave occupancy.
// Gate-interleaved rows (p=fe*4+g): C-fragment j index == gate -> in-lane
// cell update. XW = one 8B gather per mt (line-perfect: the 4 mt's of one
// M-block cover exactly one 128B line of the neighbor's XW row).
// c state [F][N] f32; h' transposed to node-major via tl. T0: skip GEMM.
template <int F, bool T0>
__launch_bounds__(512, 8)
__global__ void k_step(const u16* __restrict__ hprev, // [N][F] node-major
                       const u16* __restrict__ XW,    // [N][4F] gate-interleaved
                       const u16* __restrict__ Whp,   // [4F][F]
                       const int* __restrict__ nbr,   // [N][DEG]
                       int t,
                       float* __restrict__ cT,        // [F][N] f32
                       u16* __restrict__ hnext) {     // [N][F] node-major
  constexpr int ROWB = 2 * F;
  constexpr int KS = F / 32;
  __shared__ __align__(16) u16 Alds[64 * F];
  __shared__ __align__(16) u16 tl[128 * 24];   // [node 128][fe 16 + pad 8]
  char* ldsb = (char*)Alds;
  const int tid = threadIdx.x;
  const int w = tid >> 6;
  const int lane = tid & 63;
  const int l16 = lane & 15, lq = lane >> 4;
  const int row0 = blockIdx.x * 64;    // gate-row base
  const int col0 = blockIdx.y * 128;   // node base
  const int feb = row0 >> 2;
  const int n = col0 + w * 16 + l16;   // this thread's node

  // issue neighbor id load first (longest dependence chain)
  const int nb = nbr[(size_t)n * DEG + t];

  // stage Whp tile [row0..row0+64) x F  (skip at t=0: h==0)
  if constexpr (!T0) {
    constexpr int CH = F / 8;
    constexpr int RPI = 512 / CH;
#pragma unroll
    for (int it = 0; it < 64 / RPI; ++it) {
      int r = tid / CH + it * RPI;
      int ch = tid % CH;
      bf16x8 v = *(const bf16x8*)(Whp + (size_t)(row0 + r) * F + ch * 8);
      int bo = r * ROWB + ((ch * 16) ^ ((r & 7) << 4));
      *(bf16x8*)(ldsb + bo) = v;
    }
  }

  // XW fragments (8B each) + c state, issued before the barrier/K-loop
  u16x4 xw[4];
  float cold[4];
#pragma unroll
  for (int mt = 0; mt < 4; ++mt) {
    xw[mt] = *(const u16x4*)(XW + (size_t)nb * (4 * F) + row0 + mt * 16 + lq * 4);
    if constexpr (!T0)
      cold[mt] = cT[(size_t)(feb + mt * 4 + lq) * N_NODES + n];
  }

  f32x4 acc[4];
#pragma unroll
  for (int mt = 0; mt < 4; ++mt)
#pragma unroll
    for (int j = 0; j < 4; ++j) acc[mt][j] = 0.f;

  if constexpr (!T0) {
    __syncthreads();
    const u16* hb = hprev + (size_t)n * F + lq * 8;
#pragma unroll
    for (int ks = 0; ks < KS; ++ks) {
      bf16x8 b = *(const bf16x8*)(hb + ks * 32);
      bf16x8 a[4];
#pragma unroll
      for (int mt = 0; mt < 4; ++mt) {
        int r = mt * 16 + l16;
        int bo = r * ROWB + (((ks * 32 + lq * 8) * 2) ^ ((r & 7) << 4));
        a[mt] = *(const bf16x8*)(ldsb + bo);
      }
#pragma unroll
      for (int mt = 0; mt < 4; ++mt)
        acc[mt] = __builtin_amdgcn_mfma_f32_16x16x32_bf16(a[mt], b, acc[mt], 0, 0, 0);
    }
  }

  // fused LSTM cell update (in-lane: j = gate index i,f,g,o)
#pragma unroll
  for (int mt = 0; mt < 4; ++mt) {
    int fe = feb + mt * 4 + lq;
    float pi = acc[mt][0] + bf2f(xw[mt][0]);
    float pf = acc[mt][1] + bf2f(xw[mt][1]);
    float pg = acc[mt][2] + bf2f(xw[mt][2]);
    float po = acc[mt][3] + bf2f(xw[mt][3]);
    float cn;
    if constexpr (T0) cn = sigm(pi) * tanhfast(pg);
    else              cn = sigm(pf) * cold[mt] + sigm(pi) * tanhfast(pg);
    float hn = sigm(po) * tanhfast(cn);
    cT[(size_t)fe * N_NODES + n] = cn;
    tl[(w * 16 + l16) * 24 + mt * 4 + lq] = f2bf(hn);
  }
  __syncthreads();

  // transposed write to node-major hnext (4 threads/node, 8B each, 32B/node)
  {
    int nloc = tid >> 2, q = tid & 3;
    u16x4 v = *(const u16x4*)&tl[nloc * 24 + q * 4];
    *(u16x4*)(hnext + (size_t)(col0 + nloc) * F + feb + q * 4) = v;
  }
}

// ---- mean-pool per graph + classifier -----------------------------------
__global__ void k_pool(const u16* __restrict__ h2, const float* __restrict__ Wc,
                       const float* __restrict__ bc, float* __restrict__ out) {
  __shared__ float hg[HIDF];
  int g = blockIdx.x;
  int tid = threadIdx.x;
  float s = 0.0f;
  for (int i = 0; i < NPG; ++i) s += bf2f(h2[(size_t)(g * NPG + i) * HIDF + tid]);
  hg[tid] = s * (1.0f / NPG);
  __syncthreads();
  if (tid < OUT_F) {
    float o = bc[tid];
    for (int fe = 0; fe < HIDF; ++fe) o += hg[fe] * Wc[tid * HIDF + fe];
    out[g * OUT_F + tid] = o;
  }
}

// ---- launch -------------------------------------------------------------
extern "C" void kernel_launch(void* const* d_in, const int* in_sizes, int n_in,
                              void* d_out, int out_size, void* d_ws, size_t ws_size,
                              hipStream_t stream) {
  const float* x   = (const float*)d_in[0];
  const int*   nbr = (const int*)d_in[1];
  const float* Wi1 = (const float*)d_in[2];
  const float* Wh1 = (const float*)d_in[3];
  const float* bi1 = (const float*)d_in[4];
  const float* bh1 = (const float*)d_in[5];
  const float* Ws1 = (const float*)d_in[6];
  const float* Wn1 = (const float*)d_in[7];
  const float* b1  = (const float*)d_in[8];
  const float* Wi2 = (const float*)d_in[9];
  const float* Wh2 = (const float*)d_in[10];
  const float* bi2 = (const float*)d_in[11];
  const float* bh2 = (const float*)d_in[12];
  const float* Ws2 = (const float*)d_in[13];
  const float* Wn2 = (const float*)d_in[14];
  const float* b2  = (const float*)d_in[15];
  const float* Wc  = (const float*)d_in[16];
  const float* bc  = (const float*)d_in[17];
  float* out = (float*)d_out;

  char* ws = (char*)d_ws;
  const size_t MB = 1u << 20;
  // liveness-packed layout (high-water ~154MB):
  u16*   x16 = (u16*)(ws + 0);          //  8 MB, dead after XW1/XS1
  u16*   XW1 = (u16*)(ws + 8 * MB);     // 32 MB, dead after layer-1 steps
  u16*   XS1 = (u16*)(ws + 40 * MB);    // 16 MB; X2 written in-place by comb1
  u16*   X2  = XS1;
  u16*   hA1 = (u16*)(ws + 56 * MB);    //  8 MB
  u16*   hB1 = (u16*)(ws + 64 * MB);    //  8 MB
  float* c1  = (float*)(ws + 72 * MB);  // 16 MB f32 [128][N]
  u16*   XW2 = (u16*)(ws + 88 * MB);    // 64 MB
  u16*   XS2 = (u16*)(ws + 64 * MB);    // 16 MB (over hB1+c1, dead after comb1)
  u16*   h2o = XS2;                     // comb2 in-place
  u16*   hA2 = (u16*)(ws + 0);          // 16 MB (over x16+XW1-start, dead)
  u16*   hB2 = (u16*)(ws + 16 * MB);    // 16 MB (over XW1, dead)
  float* c2  = (float*)(ws + 32 * MB);  // 32 MB (over XW1/X2/hA1, dead)
  char* wr = ws + 152 * MB;
  size_t off = 0;
  auto alloc = [&](size_t bytes) { void* p = wr + off; off += (bytes + 255) & ~(size_t)255; return p; };
  u16*   Wip1 = (u16*)alloc(512 * 128 * 2);
  u16*   Whp1 = (u16*)alloc(512 * 128 * 2);
  float* bwp1 = (float*)alloc(512 * 4);
  u16*   Bs1  = (u16*)alloc(256 * 128 * 2);
  u16*   Bn1  = (u16*)alloc(256 * 128 * 2);
  u16*   Wip2 = (u16*)alloc(1024 * 256 * 2);
  u16*   Whp2 = (u16*)alloc(1024 * 256 * 2);
  float* bwp2 = (float*)alloc(1024 * 4);
  u16*   Bs2  = (u16*)alloc(256 * 256 * 2);
  u16*   Bn2  = (u16*)alloc(256 * 256 * 2);

  k_prep_x<<<dim3(N_NODES * IN_F / 4 / 256), dim3(256), 0, stream>>>(x, x16, N_NODES * IN_F / 4);
  k_prep_wg<<<dim3(256), dim3(256), 0, stream>>>(Wi1, Wh1, bi1, bh1, Wip1, Whp1, bwp1, IN_F);
  k_prep_wg<<<dim3(1024), dim3(256), 0, stream>>>(Wi2, Wh2, bi2, bh2, Wip2, Whp2, bwp2, HIDF);
  k_prep_cast<<<dim3(128), dim3(256), 0, stream>>>(Ws1, Wn1, Bs1, Bn1, 256 * 128);
  k_prep_cast<<<dim3(256), dim3(256), 0, stream>>>(Ws2, Wn2, Bs2, Bn2, 256 * 256);

  // ---- layer 1 ----
  k_gemm<128, 512><<<dim3(N_NODES / 64, 4), dim3(256), 0, stream>>>(x16, Wip1, bwp1, XW1);
  k_gemm<128, 256><<<dim3(N_NODES / 64, 2), dim3(256), 0, stream>>>(x16, Bs1, b1, XS1);
  {
    k_step<IN_F, true><<<dim3(8, N_NODES / 128), dim3(512), 0, stream>>>(
        hA1, XW1, Whp1, nbr, 0, c1, hA1);
    u16* hc = hA1; u16* hn = hB1;
    for (int t = 1; t < DEG; ++t) {
      k_step<IN_F, false><<<dim3(8, N_NODES / 128), dim3(512), 0, stream>>>(
          hc, XW1, Whp1, nbr, t, c1, hn);
      u16* tmp = hc; hc = hn; hn = tmp;
    }
    k_comb<128><<<dim3(N_NODES / 64, 2), dim3(256), 0, stream>>>(hc, Bn1, XS1, X2);
  }

  // ---- layer 2 ----
  k_gemm<256, 1024><<<dim3(N_NODES / 64, 8), dim3(256), 0, stream>>>(X2, Wip2, bwp2, XW2);
  k_gemm<256, 256><<<dim3(N_NODES / 64, 2), dim3(256), 0, stream>>>(X2, Bs2, b2, XS2);
  {
    k_step<HIDF, true><<<dim3(16, N_NODES / 128), dim3(512), 0, stream>>>(
        hA2, XW2, Whp2, nbr, 0, c2, hA2);
    u16* hc = hA2; u16* hn = hB2;
    for (int t = 1; t < DEG; ++t) {
      k_step<HIDF, false><<<dim3(16, N_NODES / 128), dim3(512), 0, stream>>>(
          hc, XW2, Whp2, nbr, t, c2, hn);
      u16* tmp = hc; hc = hn; hn = tmp;
    }
    k_comb<256><<<dim3(N_NODES / 64, 2), dim3(256), 0, stream>>>(hc, Bn2, XS2, h2o);
  }

  k_pool<<<dim3(N_GRAPHS), dim3(256), 0, stream>>>(h2o, Wc, bc, out);
}